// Round 2
// baseline (2988.448 us; speedup 1.0000x reference)
//
#include <hip/hip_runtime.h>
#include <cstddef>
#include <cstdint>

#define Tn 512
#define Bn 512

__device__ __forceinline__ float rlane(float v, int lane) {
    return __uint_as_float((unsigned)__builtin_amdgcn_readlane((int)__float_as_uint(v), lane));
}
__device__ __forceinline__ float sigm(float x) { return 1.0f / (1.0f + __expf(-x)); }
// tanh(x) = 1 - 2/(1+e^{2x}); inf-safe at both ends
__device__ __forceinline__ float tanhf_(float x) { return 1.0f - 2.0f / (1.0f + __expf(2.0f * x)); }

// LDS-visibility barrier WITHOUT the __syncthreads vmcnt(0) drain:
// global loads/stores stay in flight across steps (8-phase template pattern).
#define BAR_LGKM() asm volatile("s_waitcnt lgkmcnt(0)\n\ts_barrier" ::: "memory")

// ---------------------------------------------------------------------------
// Layer 0 (IN=1), both directions in one block: 4 waves =
//   wv0,1: fwd K-halves [0,32),[32,64); wv2,3: bwd K-halves.
// Lane j owns hidden unit j; wt[4][32] = 128 VGPRs (branchless init ->
// register-promoted). Per step: 32 readlane + 128 FMA -> float4 partial ->
// LDS -> raw barrier -> both waves of a dir redundantly reduce + activate
// (identical order -> bit-identical h). Per-step h store is never drained.
// ---------------------------------------------------------------------------
__global__ __launch_bounds__(256, 2) void k_lstm_l0(
    const float* __restrict__ x,
    const float* __restrict__ wih_f, const float* __restrict__ whh_f,
    const float* __restrict__ bih_f, const float* __restrict__ bhh_f,
    const float* __restrict__ wih_r, const float* __restrict__ whh_r,
    const float* __restrict__ bih_r, const float* __restrict__ bhh_r,
    float* __restrict__ h0)
{
    const int b   = blockIdx.x;
    const int tid = threadIdx.x;
    const int wv  = tid >> 6;      // 0,1 fwd ; 2,3 bwd
    const int dir = wv >> 1;
    const int kh  = wv & 1;        // K half
    const int j   = tid & 63;
    const int klo = kh * 32;

    const float* __restrict__ wih = dir ? wih_r : wih_f;
    const float* __restrict__ whh = dir ? whh_r : whh_f;
    const float* __restrict__ bih = dir ? bih_r : bih_f;
    const float* __restrict__ bhh = dir ? bhh_r : bhh_f;

    __shared__ float  xs[Tn];
    __shared__ float4 part[2][4][64];   // [buf][wave][unit]

    #pragma unroll
    for (int i = 0; i < Tn / 256; ++i) xs[i * 256 + tid] = x[b * Tn + i * 256 + tid];

    // branchless weight init -> registers
    float wt[4][32];
    float wx[4], bias[4];
    #pragma unroll
    for (int g = 0; g < 4; ++g) {
        const int r = g * 64 + j;
        wx[g]   = wih[r];                       // IN == 1
        bias[g] = bih[r] + bhh[r];
        const float* __restrict__ ws = whh + (size_t)r * 64 + klo;
        #pragma unroll
        for (int k4 = 0; k4 < 8; ++k4) {
            const float4 w4 = *reinterpret_cast<const float4*>(ws + k4 * 4);
            wt[g][k4 * 4 + 0] = w4.x; wt[g][k4 * 4 + 1] = w4.y;
            wt[g][k4 * 4 + 2] = w4.z; wt[g][k4 * 4 + 3] = w4.w;
        }
    }
    __syncthreads();   // once: xs visible (pre-loop drain is harmless)

    float h = 0.0f, c = 0.0f;
    float* __restrict__ outp = h0 + (size_t)b * Tn * 128 + dir * 64 + j;

    for (int s = 0; s < Tn; ++s) {
        const int t  = dir ? (Tn - 1 - s) : s;
        const int bf = s & 1;
        const float xt = xs[t];

        float a0 = 0.0f, a1 = 0.0f, a2 = 0.0f, a3 = 0.0f;
        #pragma unroll
        for (int kk = 0; kk < 32; ++kk) {
            const float hk = rlane(h, klo + kk);
            a0 = fmaf(hk, wt[0][kk], a0);
            a1 = fmaf(hk, wt[1][kk], a1);
            a2 = fmaf(hk, wt[2][kk], a2);
            a3 = fmaf(hk, wt[3][kk], a3);
        }
        part[bf][wv][j] = make_float4(a0, a1, a2, a3);
        BAR_LGKM();
        const float4 pA = part[bf][dir * 2 + 0][j];
        const float4 pB = part[bf][dir * 2 + 1][j];
        const float gi = fmaf(xt, wx[0], bias[0]) + pA.x + pB.x;
        const float gf = fmaf(xt, wx[1], bias[1]) + pA.y + pB.y;
        const float gg = fmaf(xt, wx[2], bias[2]) + pA.z + pB.z;
        const float go = fmaf(xt, wx[3], bias[3]) + pA.w + pB.w;
        c = sigm(gf) * c + sigm(gi) * tanhf_(gg);
        h = sigm(go) * tanhf_(c);
        if (kh == 0) outp[(size_t)t * 128] = h;   // wave-uniform branch
    }
}

// ---------------------------------------------------------------------------
// Layer 1 forward scan. 6 waves/block, K=192 split 32/wave so each wave's
// K-slice has a SINGLE broadcast source:
//   wv0,1 -> x1[0:64) ; wv2,3 -> x1[64:128) ; wv4,5 -> h[0:64).
// Branchless wt[4][32] (128 VGPRs, register-promoted). Waves 0-3 are pure
// x-partial producers (1-step-ahead register prefetch of x1; raw barriers
// never drain vmcnt so the HBM latency hides under the step). Waves 4,5
// reduce all 6 partials in a fixed order (bit-identical h) and activate.
// ---------------------------------------------------------------------------
__global__ __launch_bounds__(384, 3) void k_lstm_l1f(
    const float* __restrict__ h0,
    const float* __restrict__ wih, const float* __restrict__ whh,
    const float* __restrict__ bih, const float* __restrict__ bhh,
    float* __restrict__ h1last)
{
    const int b   = blockIdx.x;
    const int tid = threadIdx.x;
    const int wv  = tid / 64;        // 0..5
    const int j   = tid & 63;
    const int lb  = (wv & 1) * 32;   // readlane base within source
    const int kbase = wv * 32;       // global K base

    __shared__ float4 part[2][6][64];   // 12 KB

    // branchless weight + bias init -> registers
    float wt[4][32];
    float bias[4];
    #pragma unroll
    for (int g = 0; g < 4; ++g) {
        const int r = g * 64 + j;
        bias[g] = bih[r] + bhh[r];
        const float* __restrict__ ws = (kbase < 128)
            ? (wih + (size_t)r * 128 + kbase)
            : (whh + (size_t)r * 64 + (kbase - 128));
        #pragma unroll
        for (int k4 = 0; k4 < 8; ++k4) {
            const float4 w4 = *reinterpret_cast<const float4*>(ws + k4 * 4);
            wt[g][k4 * 4 + 0] = w4.x; wt[g][k4 * 4 + 1] = w4.y;
            wt[g][k4 * 4 + 2] = w4.z; wt[g][k4 * 4 + 3] = w4.w;
        }
    }

    const float* __restrict__ xrow = h0 + (size_t)b * Tn * 128;
    const int goff = (wv >> 1) * 64;     // 0 or 64 (only used by wv<4)

    float src = 0.0f;
    if (wv < 4) src = xrow[goff + j];    // t = 0 source
    float h = 0.0f, c = 0.0f;

    for (int t = 0; t < Tn; ++t) {
        const int bf = t & 1;
        // prefetch next step's source (global; floats across raw barriers)
        float nsrc = src;
        if (wv < 4) {
            const int tn = (t + 1 < Tn) ? (t + 1) : t;
            nsrc = xrow[(size_t)tn * 128 + goff + j];
        }
        float a0 = 0.0f, a1 = 0.0f, a2 = 0.0f, a3 = 0.0f;
        #pragma unroll
        for (int kk = 0; kk < 32; ++kk) {
            const float v = rlane(src, lb + kk);
            a0 = fmaf(v, wt[0][kk], a0);
            a1 = fmaf(v, wt[1][kk], a1);
            a2 = fmaf(v, wt[2][kk], a2);
            a3 = fmaf(v, wt[3][kk], a3);
        }
        part[bf][wv][j] = make_float4(a0, a1, a2, a3);
        BAR_LGKM();
        if (wv >= 4) {   // reduction + activation (waves 4,5 identical order)
            const float4 q0 = part[bf][0][j];
            const float4 q1 = part[bf][1][j];
            const float4 q2 = part[bf][2][j];
            const float4 q3 = part[bf][3][j];
            const float4 q4 = part[bf][4][j];
            const float4 q5 = part[bf][5][j];
            const float gi = bias[0] + q0.x + q1.x + q2.x + q3.x + q4.x + q5.x;
            const float gf = bias[1] + q0.y + q1.y + q2.y + q3.y + q4.y + q5.y;
            const float gg = bias[2] + q0.z + q1.z + q2.z + q3.z + q4.z + q5.z;
            const float go = bias[3] + q0.w + q1.w + q2.w + q3.w + q4.w + q5.w;
            c = sigm(gf) * c + sigm(gi) * tanhf_(gg);
            h = sigm(go) * tanhf_(c);
        }
        src = nsrc;   // waves 4,5: src tracks h below
        if (wv >= 4) src = h;
    }
    if (wv == 4) h1last[(size_t)b * 64 + j] = h;
}

// ---------------------------------------------------------------------------
// Layer-1 backward direction collapses to ONE step at t=T-1 (zero init state),
// then the final FC. One wave per batch element.
// ---------------------------------------------------------------------------
__global__ __launch_bounds__(64, 1) void k_l1r_fc(
    const float* __restrict__ h0,
    const float* __restrict__ wihr,
    const float* __restrict__ bihr, const float* __restrict__ bhhr,
    const float* __restrict__ h1last,
    const float* __restrict__ fcw, const float* __restrict__ fcb,
    float* __restrict__ out)
{
    const int b = blockIdx.x;
    const int j = threadIdx.x;
    const float* __restrict__ xrow = h0 + ((size_t)b * Tn + (Tn - 1)) * 128;
    const float x1a = xrow[j];
    const float x1b = xrow[64 + j];
    float acc[4];
    #pragma unroll
    for (int g = 0; g < 4; ++g) {
        const int r = g * 64 + j;
        float a = bihr[r] + bhhr[r];
        const float* __restrict__ wr = wihr + (size_t)r * 128;
        #pragma unroll
        for (int d4 = 0; d4 < 16; ++d4) {
            const float4 w4 = *reinterpret_cast<const float4*>(&wr[d4 * 4]);
            a = fmaf(rlane(x1a, d4 * 4 + 0), w4.x, a);
            a = fmaf(rlane(x1a, d4 * 4 + 1), w4.y, a);
            a = fmaf(rlane(x1a, d4 * 4 + 2), w4.z, a);
            a = fmaf(rlane(x1a, d4 * 4 + 3), w4.w, a);
        }
        #pragma unroll
        for (int d4 = 0; d4 < 16; ++d4) {
            const float4 w4 = *reinterpret_cast<const float4*>(&wr[64 + d4 * 4]);
            a = fmaf(rlane(x1b, d4 * 4 + 0), w4.x, a);
            a = fmaf(rlane(x1b, d4 * 4 + 1), w4.y, a);
            a = fmaf(rlane(x1b, d4 * 4 + 2), w4.z, a);
            a = fmaf(rlane(x1b, d4 * 4 + 3), w4.w, a);
        }
        acc[g] = a;
    }
    const float cr = sigm(acc[0]) * tanhf_(acc[2]);
    const float hr = sigm(acc[3]) * tanhf_(cr);
    float v = h1last[(size_t)b * 64 + j] * fcw[j] + hr * fcw[64 + j];
    #pragma unroll
    for (int off = 32; off > 0; off >>= 1) v += __shfl_xor(v, off, 64);
    if (j == 0) out[b] = v + fcb[0];
}

// ---------------------------------------------------------------------------
extern "C" void kernel_launch(void* const* d_in, const int* in_sizes, int n_in,
                              void* d_out, int out_size, void* d_ws, size_t ws_size,
                              hipStream_t stream)
{
    const float* x       = (const float*)d_in[0];
    const float* wih_l0  = (const float*)d_in[1];
    const float* whh_l0  = (const float*)d_in[2];
    const float* bih_l0  = (const float*)d_in[3];
    const float* bhh_l0  = (const float*)d_in[4];
    const float* wih_l0r = (const float*)d_in[5];
    const float* whh_l0r = (const float*)d_in[6];
    const float* bih_l0r = (const float*)d_in[7];
    const float* bhh_l0r = (const float*)d_in[8];
    const float* wih_l1  = (const float*)d_in[9];
    const float* whh_l1  = (const float*)d_in[10];
    const float* bih_l1  = (const float*)d_in[11];
    const float* bhh_l1  = (const float*)d_in[12];
    const float* wih_l1r = (const float*)d_in[13];
    const float* whh_l1r = (const float*)d_in[14];
    const float* bih_l1r = (const float*)d_in[15];
    const float* bhh_l1r = (const float*)d_in[16];
    const float* fcw     = (const float*)d_in[17];
    const float* fcb     = (const float*)d_in[18];
    (void)whh_l1r; (void)in_sizes; (void)n_in; (void)out_size;

    // ws layout: h0 [512][512][128] f32 (134.2 MB) + h1last [512][64] f32
    float* h0     = (float*)d_ws;
    float* h1last = h0 + (size_t)Bn * Tn * 128;
    (void)ws_size;

    k_lstm_l0<<<dim3(Bn), dim3(256), 0, stream>>>(
        x, wih_l0, whh_l0, bih_l0, bhh_l0,
        wih_l0r, whh_l0r, bih_l0r, bhh_l0r, h0);
    k_lstm_l1f<<<dim3(Bn), dim3(384), 0, stream>>>(
        h0, wih_l1, whh_l1, bih_l1, bhh_l1, h1last);
    k_l1r_fc<<<dim3(Bn), dim3(64), 0, stream>>>(
        h0, wih_l1r, bih_l1r, bhh_l1r, h1last, fcw, fcb, (float*)d_out);
}

// Round 3
// 1172.185 us; speedup vs baseline: 2.5495x; 2.5495x over previous
//
#include <hip/hip_runtime.h>
#include <cstddef>
#include <cstdint>

#define Tn 512
#define Bn 512

__device__ __forceinline__ float rlane(float v, int lane) {
    return __uint_as_float((unsigned)__builtin_amdgcn_readlane((int)__float_as_uint(v), lane));
}
__device__ __forceinline__ float sigm(float x) { return 1.0f / (1.0f + __expf(-x)); }
// tanh(x) = 1 - 2/(1+e^{2x}); inf-safe at both ends
__device__ __forceinline__ float tanhf_(float x) { return 1.0f - 2.0f / (1.0f + __expf(2.0f * x)); }

// LDS-visibility barrier WITHOUT the __syncthreads vmcnt(0) drain:
// global loads/stores stay in flight across steps.
#define BAR_LGKM() asm volatile("s_waitcnt lgkmcnt(0)\n\ts_barrier" ::: "memory")

// ---------------------------------------------------------------------------
// Layer 0 (IN=1), both directions. Block = 512 threads = 4 (b,dir) tasks x
// 2 waves; K=64 split 32/wave -> wt[4][32] = 128 VGPRs (+~40 overhead) under
// the 256-VGPR budget of __launch_bounds__(512,2)  [2 waves/SIMD, 1 block/CU].
// Per step: 32 readlane + 128 FMA -> float4 partial -> LDS -> raw barrier ->
// both waves of the task redundantly reduce + activate (identical order ->
// bit-identical h). Per-step h store is never vmcnt-drained.
// ---------------------------------------------------------------------------
__global__ __launch_bounds__(512, 2) void k_lstm_l0(
    const float* __restrict__ x,
    const float* __restrict__ wih_f, const float* __restrict__ whh_f,
    const float* __restrict__ bih_f, const float* __restrict__ bhh_f,
    const float* __restrict__ wih_r, const float* __restrict__ whh_r,
    const float* __restrict__ bih_r, const float* __restrict__ bhh_r,
    float* __restrict__ h0)
{
    const int tid = threadIdx.x;
    const int ti  = tid >> 7;        // task in block: 0..3
    const int kh  = (tid >> 6) & 1;  // K half
    const int j   = tid & 63;        // hidden unit
    const int e   = ti >> 1;         // batch element in block
    const int dir = ti & 1;
    const int b   = blockIdx.x * 2 + e;
    const int klo = kh * 32;

    const float* __restrict__ wih = dir ? wih_r : wih_f;
    const float* __restrict__ whh = dir ? whh_r : whh_f;
    const float* __restrict__ bih = dir ? bih_r : bih_f;
    const float* __restrict__ bhh = dir ? bhh_r : bhh_f;

    __shared__ float  xs[2][Tn];            // 4 KB
    __shared__ float4 part[4][2][2][64];    // [task][buf][kh][unit], 16 KB

    // stage both batch rows of x (512 threads, 2 floats each)
    xs[0][tid] = x[(size_t)(blockIdx.x * 2 + 0) * Tn + tid];
    xs[1][tid] = x[(size_t)(blockIdx.x * 2 + 1) * Tn + tid];

    // branchless weight init -> registers
    float wt[4][32];
    float wx[4], bias[4];
    #pragma unroll
    for (int g = 0; g < 4; ++g) {
        const int r = g * 64 + j;
        wx[g]   = wih[r];                   // IN == 1
        bias[g] = bih[r] + bhh[r];
        const float* __restrict__ ws = whh + (size_t)r * 64 + klo;
        #pragma unroll
        for (int k4 = 0; k4 < 8; ++k4) {
            const float4 w4 = *reinterpret_cast<const float4*>(ws + k4 * 4);
            wt[g][k4 * 4 + 0] = w4.x; wt[g][k4 * 4 + 1] = w4.y;
            wt[g][k4 * 4 + 2] = w4.z; wt[g][k4 * 4 + 3] = w4.w;
        }
    }
    __syncthreads();   // once: xs visible (pre-loop drain is harmless)

    float h = 0.0f, c = 0.0f;
    float* __restrict__ outp = h0 + (size_t)b * Tn * 128 + dir * 64 + j;

    for (int s = 0; s < Tn; ++s) {
        const int t  = dir ? (Tn - 1 - s) : s;
        const int bf = s & 1;
        const float xt = xs[e][t];

        float a0 = 0.0f, a1 = 0.0f, a2 = 0.0f, a3 = 0.0f;
        #pragma unroll
        for (int kk = 0; kk < 32; ++kk) {
            const float hk = rlane(h, klo + kk);
            a0 = fmaf(hk, wt[0][kk], a0);
            a1 = fmaf(hk, wt[1][kk], a1);
            a2 = fmaf(hk, wt[2][kk], a2);
            a3 = fmaf(hk, wt[3][kk], a3);
        }
        part[ti][bf][kh][j] = make_float4(a0, a1, a2, a3);
        BAR_LGKM();
        const float4 pA = part[ti][bf][0][j];
        const float4 pB = part[ti][bf][1][j];
        const float gi = fmaf(xt, wx[0], bias[0]) + pA.x + pB.x;
        const float gf = fmaf(xt, wx[1], bias[1]) + pA.y + pB.y;
        const float gg = fmaf(xt, wx[2], bias[2]) + pA.z + pB.z;
        const float go = fmaf(xt, wx[3], bias[3]) + pA.w + pB.w;
        c = sigm(gf) * c + sigm(gi) * tanhf_(gg);
        h = sigm(go) * tanhf_(c);
        if (kh == 0) outp[(size_t)t * 128] = h;   // wave-uniform branch
    }
}

// ---------------------------------------------------------------------------
// Layer 1 forward scan, input GEMM fused (K = 128 input + 64 recurrent = 192).
// Block = 512 threads = 2 batch elements x 4 waves; K split 48/wave ->
// wt[4][48] = 192 VGPRs (+~40) under the 256 budget of (512,2).
//   wv0: x1a[0:48)   wv1: x1a[48:64)+x1b[0:32)
//   wv2: x1b[32:64)+h[0:16)   wv3: h[16:64)
// Waves 0,1 are pure x-partial producers with 1-step-ahead register prefetch
// (raw barriers never drain vmcnt -> HBM latency hides under the step).
// Waves 2,3 redundantly reduce all 4 partials in fixed order + activate.
// ---------------------------------------------------------------------------
__global__ __launch_bounds__(512, 2) void k_lstm_l1f(
    const float* __restrict__ h0,
    const float* __restrict__ wih, const float* __restrict__ whh,
    const float* __restrict__ bih, const float* __restrict__ bhh,
    float* __restrict__ h1last)
{
    const int tid = threadIdx.x;
    const int e   = tid >> 8;        // batch element in block
    const int wv  = (tid >> 6) & 3;  // 0..3
    const int j   = tid & 63;
    const int b   = blockIdx.x * 2 + e;
    const int kbase = wv * 48;

    __shared__ float4 part[2][2][4][64];   // [e][buf][wv][unit], 16 KB

    // branchless weight + bias init -> registers
    float wt[4][48];
    float bias[4];
    #pragma unroll
    for (int g = 0; g < 4; ++g) {
        const int r = g * 64 + j;
        bias[g] = bih[r] + bhh[r];
        #pragma unroll
        for (int k4 = 0; k4 < 12; ++k4) {
            const int k = kbase + k4 * 4;
            const float* __restrict__ src = (k < 128)
                ? (wih + (size_t)r * 128 + k)
                : (whh + (size_t)r * 64 + (k - 128));
            const float4 w4 = *reinterpret_cast<const float4*>(src);
            wt[g][k4 * 4 + 0] = w4.x; wt[g][k4 * 4 + 1] = w4.y;
            wt[g][k4 * 4 + 2] = w4.z; wt[g][k4 * 4 + 3] = w4.w;
        }
    }

    const float* __restrict__ xrow = h0 + (size_t)b * Tn * 128;

    // t = 0 sources
    float x1a = 0.0f, x1b = 0.0f;
    if (wv <= 1) x1a = xrow[j];
    if (wv == 1 || wv == 2) x1b = xrow[64 + j];
    float h = 0.0f, c = 0.0f;

    for (int t = 0; t < Tn; ++t) {
        const int bf = t & 1;
        // prefetch next step's sources (globals float across raw barriers)
        const int tn = (t + 1 < Tn) ? (t + 1) : t;
        float nx1a = 0.0f, nx1b = 0.0f;
        if (wv <= 1)            nx1a = xrow[(size_t)tn * 128 + j];
        if (wv == 1 || wv == 2) nx1b = xrow[(size_t)tn * 128 + 64 + j];

        float a0 = 0.0f, a1 = 0.0f, a2 = 0.0f, a3 = 0.0f;
        if (wv == 0) {
            #pragma unroll
            for (int kk = 0; kk < 48; ++kk) {
                const float v = rlane(x1a, kk);
                a0 = fmaf(v, wt[0][kk], a0); a1 = fmaf(v, wt[1][kk], a1);
                a2 = fmaf(v, wt[2][kk], a2); a3 = fmaf(v, wt[3][kk], a3);
            }
        } else if (wv == 1) {
            #pragma unroll
            for (int kk = 0; kk < 48; ++kk) {
                const float v = (kk < 16) ? rlane(x1a, 48 + kk) : rlane(x1b, kk - 16);
                a0 = fmaf(v, wt[0][kk], a0); a1 = fmaf(v, wt[1][kk], a1);
                a2 = fmaf(v, wt[2][kk], a2); a3 = fmaf(v, wt[3][kk], a3);
            }
        } else if (wv == 2) {
            #pragma unroll
            for (int kk = 0; kk < 48; ++kk) {
                const float v = (kk < 32) ? rlane(x1b, 32 + kk) : rlane(h, kk - 32);
                a0 = fmaf(v, wt[0][kk], a0); a1 = fmaf(v, wt[1][kk], a1);
                a2 = fmaf(v, wt[2][kk], a2); a3 = fmaf(v, wt[3][kk], a3);
            }
        } else {
            #pragma unroll
            for (int kk = 0; kk < 48; ++kk) {
                const float v = rlane(h, 16 + kk);
                a0 = fmaf(v, wt[0][kk], a0); a1 = fmaf(v, wt[1][kk], a1);
                a2 = fmaf(v, wt[2][kk], a2); a3 = fmaf(v, wt[3][kk], a3);
            }
        }
        part[e][bf][wv][j] = make_float4(a0, a1, a2, a3);
        BAR_LGKM();
        if (wv >= 2) {   // waves 2,3: identical fixed-order reduce + activate
            const float4 q0 = part[e][bf][0][j];
            const float4 q1 = part[e][bf][1][j];
            const float4 q2 = part[e][bf][2][j];
            const float4 q3 = part[e][bf][3][j];
            const float gi = bias[0] + q0.x + q1.x + q2.x + q3.x;
            const float gf = bias[1] + q0.y + q1.y + q2.y + q3.y;
            const float gg = bias[2] + q0.z + q1.z + q2.z + q3.z;
            const float go = bias[3] + q0.w + q1.w + q2.w + q3.w;
            c = sigm(gf) * c + sigm(gi) * tanhf_(gg);
            h = sigm(go) * tanhf_(c);
        }
        x1a = nx1a; x1b = nx1b;
    }
    if (wv == 2) h1last[(size_t)b * 64 + j] = h;
}

// ---------------------------------------------------------------------------
// Layer-1 backward direction collapses to ONE step at t=T-1 (zero init state),
// then the final FC. One wave per batch element.
// ---------------------------------------------------------------------------
__global__ __launch_bounds__(64, 1) void k_l1r_fc(
    const float* __restrict__ h0,
    const float* __restrict__ wihr,
    const float* __restrict__ bihr, const float* __restrict__ bhhr,
    const float* __restrict__ h1last,
    const float* __restrict__ fcw, const float* __restrict__ fcb,
    float* __restrict__ out)
{
    const int b = blockIdx.x;
    const int j = threadIdx.x;
    const float* __restrict__ xrow = h0 + ((size_t)b * Tn + (Tn - 1)) * 128;
    const float x1a = xrow[j];
    const float x1b = xrow[64 + j];
    float acc[4];
    #pragma unroll
    for (int g = 0; g < 4; ++g) {
        const int r = g * 64 + j;
        float a = bihr[r] + bhhr[r];
        const float* __restrict__ wr = wihr + (size_t)r * 128;
        #pragma unroll
        for (int d4 = 0; d4 < 16; ++d4) {
            const float4 w4 = *reinterpret_cast<const float4*>(&wr[d4 * 4]);
            a = fmaf(rlane(x1a, d4 * 4 + 0), w4.x, a);
            a = fmaf(rlane(x1a, d4 * 4 + 1), w4.y, a);
            a = fmaf(rlane(x1a, d4 * 4 + 2), w4.z, a);
            a = fmaf(rlane(x1a, d4 * 4 + 3), w4.w, a);
        }
        #pragma unroll
        for (int d4 = 0; d4 < 16; ++d4) {
            const float4 w4 = *reinterpret_cast<const float4*>(&wr[64 + d4 * 4]);
            a = fmaf(rlane(x1b, d4 * 4 + 0), w4.x, a);
            a = fmaf(rlane(x1b, d4 * 4 + 1), w4.y, a);
            a = fmaf(rlane(x1b, d4 * 4 + 2), w4.z, a);
            a = fmaf(rlane(x1b, d4 * 4 + 3), w4.w, a);
        }
        acc[g] = a;
    }
    const float cr = sigm(acc[0]) * tanhf_(acc[2]);
    const float hr = sigm(acc[3]) * tanhf_(cr);
    float v = h1last[(size_t)b * 64 + j] * fcw[j] + hr * fcw[64 + j];
    #pragma unroll
    for (int off = 32; off > 0; off >>= 1) v += __shfl_xor(v, off, 64);
    if (j == 0) out[b] = v + fcb[0];
}

// ---------------------------------------------------------------------------
extern "C" void kernel_launch(void* const* d_in, const int* in_sizes, int n_in,
                              void* d_out, int out_size, void* d_ws, size_t ws_size,
                              hipStream_t stream)
{
    const float* x       = (const float*)d_in[0];
    const float* wih_l0  = (const float*)d_in[1];
    const float* whh_l0  = (const float*)d_in[2];
    const float* bih_l0  = (const float*)d_in[3];
    const float* bhh_l0  = (const float*)d_in[4];
    const float* wih_l0r = (const float*)d_in[5];
    const float* whh_l0r = (const float*)d_in[6];
    const float* bih_l0r = (const float*)d_in[7];
    const float* bhh_l0r = (const float*)d_in[8];
    const float* wih_l1  = (const float*)d_in[9];
    const float* whh_l1  = (const float*)d_in[10];
    const float* bih_l1  = (const float*)d_in[11];
    const float* bhh_l1  = (const float*)d_in[12];
    const float* wih_l1r = (const float*)d_in[13];
    const float* whh_l1r = (const float*)d_in[14];
    const float* bih_l1r = (const float*)d_in[15];
    const float* bhh_l1r = (const float*)d_in[16];
    const float* fcw     = (const float*)d_in[17];
    const float* fcb     = (const float*)d_in[18];
    (void)whh_l1r; (void)in_sizes; (void)n_in; (void)out_size;

    // ws layout: h0 [512][512][128] f32 (134.2 MB) + h1last [512][64] f32
    float* h0     = (float*)d_ws;
    float* h1last = h0 + (size_t)Bn * Tn * 128;
    (void)ws_size;

    k_lstm_l0<<<dim3(Bn / 2), dim3(512), 0, stream>>>(
        x, wih_l0, whh_l0, bih_l0, bhh_l0,
        wih_l0r, whh_l0r, bih_l0r, bhh_l0r, h0);
    k_lstm_l1f<<<dim3(Bn / 2), dim3(512), 0, stream>>>(
        h0, wih_l1, whh_l1, bih_l1, bhh_l1, h1last);
    k_l1r_fc<<<dim3(Bn), dim3(64), 0, stream>>>(
        h0, wih_l1r, bih_l1r, bhh_l1r, h1last, fcw, fcb, (float*)d_out);
}